// Round 6
// baseline (292.793 us; speedup 1.0000x reference)
//
#include <hip/hip_runtime.h>
#include <hip/hip_bf16.h>

#define DIM 2048
#define NH 16
#define NKV 4
#define HD 128
#define S_LEN 2048
#define BATCH 2
#define QKV_N 3072
#define NEGBIG -1.0e30f

typedef __attribute__((ext_vector_type(8))) short bf16x8;
typedef __attribute__((ext_vector_type(4))) float f32x4;
typedef unsigned short ushort_t;

#define GLOAD_LDS16(gp, lp)                                                       \
    __builtin_amdgcn_global_load_lds(                                             \
        (const __attribute__((address_space(1))) void*)(gp),                      \
        (__attribute__((address_space(3))) void*)(lp), 16, 0, 0)

static __device__ __forceinline__ ushort_t f2bf(float f) {
    union { float f; unsigned u; } v; v.f = f;
    unsigned r = v.u + 0x7fffu + ((v.u >> 16) & 1u);
    return (ushort_t)(r >> 16);
}
static __device__ __forceinline__ float bf2f(ushort_t u) {
    union { unsigned u; float f; } v; v.u = ((unsigned)u) << 16;
    return v.f;
}
static __device__ __forceinline__ unsigned pk2bf(float a, float b) {
    unsigned r;
    __asm__ volatile("v_cvt_pk_bf16_f32 %0, %1, %2" : "=v"(r) : "v"(a), "v"(b));
    return r;
}

// Merged fp32->bf16: x | Wq|Wk|Wv -> Wqkvb | Wp -> Wpb, one launch.
__global__ __launch_bounds__(256) void cvt_in(const float* __restrict__ x,
                                              const float* __restrict__ Wq,
                                              const float* __restrict__ Wk,
                                              const float* __restrict__ Wv,
                                              const float* __restrict__ Wp,
                                              ushort_t* __restrict__ xb,
                                              ushort_t* __restrict__ Wqkvb,
                                              ushort_t* __restrict__ Wpb) {
    int i = (blockIdx.x * 256 + threadIdx.x) * 4;
    const float* src;
    ushort_t* dst;
    int soff, doff;
    if (i < 8388608) {
        src = x; dst = xb; soff = i; doff = i;
    } else if (i < 14680064) {
        int j = i - 8388608;
        dst = Wqkvb; doff = j;
        if (j < 4194304) { src = Wq; soff = j; }
        else if (j < 5242880) { src = Wk; soff = j - 4194304; }
        else { src = Wv; soff = j - 5242880; }
    } else {
        int j = i - 14680064;
        src = Wp; dst = Wpb; soff = j; doff = j;
    }
    float4 v = *(const float4*)&src[soff];
    uint2 o = {pk2bf(v.x, v.y), pk2bf(v.z, v.w)};
    *(uint2*)&dst[doff] = o;
}

#define FENCE() __asm__ __volatile__("" ::: "memory")
#define BARRIER() do { FENCE(); __builtin_amdgcn_s_barrier(); FENCE(); } while (0)
#define WAITVM(n) __asm__ __volatile__("s_waitcnt vmcnt(" #n ")" ::: "memory")

#define STG(LDSA, GP, rowb) do {                                                  \
    const int r_ = (rowb) + rsub;                                                 \
    GLOAD_LDS16(&(GP)[(size_t)r_ * 2048 + kk0_ + ((csw0 ^ (r_ & 7)) * 8)],        \
                &(LDSA)[(rowb) * 64]);                                            \
} while (0)

// ---------------------------------------------------------------------------
// 256x256 8-phase GEMM (qkv). Single barrier/phase, counted vmcnt(6), XCD
// chunk swizzle. NO explicit lgkmcnt(0): every ds_read is consumed by this
// phase's MFMA (SSA dep), lgkmcnt retires in order, so the compiler's counted
// waits drain all reads before the phase-end barrier while letting later
// reads overlap earlier MFMAs.
// ---------------------------------------------------------------------------
#define STAGE_HT(AB, BB, kt, ht) do {                                             \
    const int kt_ = (kt) < 31 ? (kt) : 31;                                        \
    const int kk0_ = kt_ * 64;                                                    \
    if ((ht) == 0)      { STG(BB, Bp, w8);       STG(BB, Bp, 64 + w8);  }         \
    else if ((ht) == 1) { STG(BB, Bp, 128 + w8); STG(BB, Bp, 192 + w8); }         \
    else if ((ht) == 2) { STG(AB, Ap, w8);       STG(AB, Ap, 128 + w8); }         \
    else                { STG(AB, Ap, 64 + w8);  STG(AB, Ap, 192 + w8); }         \
} while (0)

#define DSA(mtb, AS) do {                                                         \
    _Pragma("unroll") for (int dm = 0; dm < 2; dm++)                              \
    _Pragma("unroll") for (int ks = 0; ks < 2; ks++) {                            \
        const int row = wr * 128 + ((mtb) + dm) * 16 + m16;                       \
        af[dm][ks] = *(const bf16x8*)&(AS)[row * 64 +                             \
                                           (((ks * 4 + quad) ^ (row & 7)) * 8)];  \
    }                                                                             \
} while (0)

#define DSB(BS) do {                                                              \
    _Pragma("unroll") for (int nt = 0; nt < 4; nt++)                              \
    _Pragma("unroll") for (int ks = 0; ks < 2; ks++) {                            \
        const int row = wc * 64 + nt * 16 + m16;                                  \
        bfr[nt][ks] = *(const bf16x8*)&(BS)[row * 64 +                            \
                                            (((ks * 4 + quad) ^ (row & 7)) * 8)]; \
    }                                                                             \
} while (0)

#define MMA(mtb) do {                                                             \
    __builtin_amdgcn_s_setprio(1);                                                \
    _Pragma("unroll") for (int ks = 0; ks < 2; ks++)                              \
    _Pragma("unroll") for (int dm = 0; dm < 2; dm++)                              \
    _Pragma("unroll") for (int nt = 0; nt < 4; nt++)                              \
        acc[(mtb) + dm][nt] = __builtin_amdgcn_mfma_f32_16x16x32_bf16(            \
            af[dm][ks], bfr[nt][ks], acc[(mtb) + dm][nt], 0, 0, 0);               \
    __builtin_amdgcn_s_setprio(0);                                                \
} while (0)

__global__ __launch_bounds__(512, 2) void gemm256_qkv(const ushort_t* __restrict__ A,
                                                      const ushort_t* __restrict__ B,
                                                      ushort_t* __restrict__ qkv,
                                                      ushort_t* __restrict__ vt,
                                                      const float* __restrict__ gain) {
    __shared__ __align__(16) ushort_t sh[4][256 * 64];  // A0 A1 B0 B1; reused as Cs
    const int t = threadIdx.x;
    const int lane = t & 63;
    const int wave = t >> 6;
    const int m16 = lane & 15;
    const int quad = lane >> 4;
    const int wr = wave >> 2;
    const int wc = wave & 3;
    const int nwg = gridDim.x * gridDim.y;
    const int wgid = blockIdx.y * gridDim.x + blockIdx.x;
    const int wg2 = (wgid & 7) * (nwg >> 3) + (wgid >> 3);
    const int bx = wg2 % gridDim.x;
    const int m0 = (wg2 / gridDim.x) * 256;
    const int n0 = bx * 256;
    const int rsub = lane >> 3;
    const int csw0 = lane & 7;
    const int w8 = wave * 8;
    const ushort_t* Ap = A + (size_t)m0 * 2048;
    const ushort_t* Bp = B + (size_t)n0 * 2048;

    f32x4 acc[8][4];
#pragma unroll
    for (int i = 0; i < 8; i++)
#pragma unroll
        for (int j = 0; j < 4; j++) acc[i][j] = (f32x4){0.f, 0.f, 0.f, 0.f};

    STAGE_HT(sh[0], sh[2], 0, 0);
    STAGE_HT(sh[0], sh[2], 0, 1);
    STAGE_HT(sh[0], sh[2], 0, 2);
    STAGE_HT(sh[0], sh[2], 0, 3);
    STAGE_HT(sh[1], sh[3], 1, 0);
    STAGE_HT(sh[1], sh[3], 1, 1);
    STAGE_HT(sh[1], sh[3], 1, 2);
    WAITVM(6);
    BARRIER();

    bf16x8 bfr[4][2];
#pragma unroll 1
    for (int i = 0; i < 16; ++i) {
        const int tb = 2 * i;
        {   bf16x8 af[2][2];
            DSA(0, sh[0]); DSB(sh[2]);
            STAGE_HT(sh[1], sh[3], tb + 1, 3);
            MMA(0); BARRIER();
        }
        {   bf16x8 af[2][2];
            DSA(2, sh[0]);
            STAGE_HT(sh[0], sh[2], tb + 2, 0);
            MMA(2); BARRIER();
        }
        {   bf16x8 af[2][2];
            DSA(4, sh[0]);
            STAGE_HT(sh[0], sh[2], tb + 2, 1);
            MMA(4); BARRIER();
        }
        {   bf16x8 af[2][2];
            DSA(6, sh[0]);
            STAGE_HT(sh[0], sh[2], tb + 2, 2);
            WAITVM(6);
            MMA(6); BARRIER();
        }
        {   bf16x8 af[2][2];
            DSA(0, sh[1]); DSB(sh[3]);
            STAGE_HT(sh[0], sh[2], tb + 2, 3);
            MMA(0); BARRIER();
        }
        {   bf16x8 af[2][2];
            DSA(2, sh[1]);
            STAGE_HT(sh[1], sh[3], tb + 3, 0);
            MMA(2); BARRIER();
        }
        {   bf16x8 af[2][2];
            DSA(4, sh[1]);
            STAGE_HT(sh[1], sh[3], tb + 3, 1);
            MMA(4); BARRIER();
        }
        {   bf16x8 af[2][2];
            DSA(6, sh[1]);
            STAGE_HT(sh[1], sh[3], tb + 3, 2);
            WAITVM(6);
            MMA(6); BARRIER();
        }
    }
    WAITVM(0);
    __syncthreads();

    // Fused qkv epilogue via 256x256 bf16 C-stage in LDS.
    ushort_t* Cs = &sh[0][0];
#pragma unroll
    for (int mt = 0; mt < 8; mt++)
#pragma unroll
        for (int r = 0; r < 4; r++) {
            const int row = wr * 128 + mt * 16 + quad * 4 + r;
#pragma unroll
            for (int nt = 0; nt < 4; nt++)
                Cs[row * 256 + wc * 64 + nt * 16 + m16] = f2bf(acc[mt][nt][r]);
        }
    __syncthreads();

    if (bx < 10) {
        // Q (bx<8) / K (bx 8,9): tile = 2 heads. RMSNorm + RoPE (+gain).
        const float invf = exp2f(-0.20762050593046f * (float)lane);
        float gg[2];
#pragma unroll
        for (int hh = 0; hh < 2; hh++) gg[hh] = (bx < 8) ? gain[bx * 2 + hh] : 1.0f;
#pragma unroll 2
        for (int i = 0; i < 32; i++) {
            const int row = wave * 32 + i;
            const int m = m0 + row;
            const int s = m & (S_LEN - 1);
            const float fr = (float)s * invf;
            const float c = cosf(fr), sn = sinf(fr);
#pragma unroll
            for (int hh = 0; hh < 2; hh++) {
                float x1 = bf2f(Cs[row * 256 + hh * 128 + lane]);
                float x2 = bf2f(Cs[row * 256 + hh * 128 + 64 + lane]);
                float ss = x1 * x1 + x2 * x2;
#pragma unroll
                for (int mm = 32; mm >= 1; mm >>= 1) ss += __shfl_xor(ss, mm, 64);
                const float rms = rsqrtf(ss * (1.0f / 128.0f) + 1.1920928955078125e-07f);
                x1 *= rms; x2 *= rms;
                ushort_t* dst = qkv + (size_t)m * QKV_N + bx * 256 + hh * 128;
                dst[lane] = f2bf((x1 * c + x2 * sn) * gg[hh]);
                dst[lane + 64] = f2bf((x2 * c - x1 * sn) * gg[hh]);
            }
        }
    } else {
        // V: transpose-out 2 kv heads -> vt[b][kv][d][s]
        const int half = t >> 8;
        const int tt = t & 255;
        const int d = tt >> 1;
        const int so = (tt & 1) * 128;
        const int b = m0 >> 11;
        const int s0 = m0 & (S_LEN - 1);
        const int kv = (bx - 10) * 2 + half;
        ushort_t* dst = vt + ((size_t)(b * NKV + kv) * HD + d) * S_LEN + s0 + so;
#pragma unroll
        for (int j0 = 0; j0 < 128; j0 += 8) {
            ushort_t tmp[8];
#pragma unroll
            for (int j = 0; j < 8; j++) tmp[j] = Cs[(so + j0 + j) * 256 + half * 128 + d];
            *(uint4*)&dst[j0] = *(uint4*)tmp;
        }
    }
}

// ---------------------------------------------------------------------------
// Proj GEMM: BM=128 x BN=256, BK=64, 512 threads (2Mx4N waves, 64x64/wave).
// Grid = 8x32 = 256 blocks -> 1 block/CU, 100% machine fill.
// 4 phases per 2 K-tiles, single barrier/phase, counted vmcnt(4).
// No explicit lgkmcnt (see qkv comment).
// ---------------------------------------------------------------------------
#define P_STAGE_A(AB, kt) do {                                                    \
    const int kt_ = (kt) < 31 ? (kt) : 31;                                        \
    const int kk0_ = kt_ * 64;                                                    \
    STG(AB, Ap, w8); STG(AB, Ap, 64 + w8);                                        \
} while (0)
#define P_STAGE_BLO(BB, kt) do {                                                  \
    const int kt_ = (kt) < 31 ? (kt) : 31;                                        \
    const int kk0_ = kt_ * 64;                                                    \
    STG(BB, Bp, w8); STG(BB, Bp, 64 + w8);                                        \
} while (0)
#define P_STAGE_BHI(BB, kt) do {                                                  \
    const int kt_ = (kt) < 31 ? (kt) : 31;                                        \
    const int kk0_ = kt_ * 64;                                                    \
    STG(BB, Bp, 128 + w8); STG(BB, Bp, 192 + w8);                                 \
} while (0)

#define P_DSA8(AS) do {                                                           \
    _Pragma("unroll") for (int mt = 0; mt < 4; mt++)                              \
    _Pragma("unroll") for (int ks = 0; ks < 2; ks++) {                            \
        const int row = wr * 64 + mt * 16 + m16;                                  \
        af[mt][ks] = *(const bf16x8*)&(AS)[row * 64 +                             \
                                           (((ks * 4 + quad) ^ (row & 7)) * 8)];  \
    }                                                                             \
} while (0)
#define P_DSB(BS, base, arr) do {                                                 \
    _Pragma("unroll") for (int nt = 0; nt < 2; nt++)                              \
    _Pragma("unroll") for (int ks = 0; ks < 2; ks++) {                            \
        const int row = wc * 64 + (base) + nt * 16 + m16;                         \
        arr[nt][ks] = *(const bf16x8*)&(BS)[row * 64 +                            \
                                            (((ks * 4 + quad) ^ (row & 7)) * 8)]; \
    }                                                                             \
} while (0)

#define P_MMA(ntb, arr) do {                                                      \
    __builtin_amdgcn_s_setprio(1);                                                \
    _Pragma("unroll") for (int ks = 0; ks < 2; ks++)                              \
    _Pragma("unroll") for (int mt = 0; mt < 4; mt++)                              \
    _Pragma("unroll") for (int nt = 0; nt < 2; nt++)                              \
        acc[mt][(ntb) + nt] = __builtin_amdgcn_mfma_f32_16x16x32_bf16(            \
            af[mt][ks], arr[nt][ks], acc[mt][(ntb) + nt], 0, 0, 0);               \
    __builtin_amdgcn_s_setprio(0);                                                \
} while (0)

__global__ __launch_bounds__(512, 2) void gemm_proj(const ushort_t* __restrict__ A,
                                                    const ushort_t* __restrict__ B,
                                                    float* __restrict__ C) {
    __shared__ __align__(16) ushort_t Asb[2][128 * 64];  // 2 x 16 KB
    __shared__ __align__(16) ushort_t Bsb[2][256 * 64];  // 2 x 32 KB
    const int t = threadIdx.x;
    const int lane = t & 63;
    const int wave = t >> 6;
    const int m16 = lane & 15;
    const int quad = lane >> 4;
    const int wr = wave >> 2;
    const int wc = wave & 3;
    const int nwg = gridDim.x * gridDim.y;           // 8 x 32 = 256
    const int wgid = blockIdx.y * gridDim.x + blockIdx.x;
    const int wg2 = (wgid & 7) * (nwg >> 3) + (wgid >> 3);
    const int bx = wg2 % gridDim.x;
    const int m0 = (wg2 / gridDim.x) * 128;
    const int n0 = bx * 256;
    const int rsub = lane >> 3;
    const int csw0 = lane & 7;
    const int w8 = wave * 8;
    const ushort_t* Ap = A + (size_t)m0 * 2048;
    const ushort_t* Bp = B + (size_t)n0 * 2048;

    f32x4 acc[4][4];
#pragma unroll
    for (int i = 0; i < 4; i++)
#pragma unroll
        for (int j = 0; j < 4; j++) acc[i][j] = (f32x4){0.f, 0.f, 0.f, 0.f};

    // Prologue: t0 complete (6 loads), t1.A+Blo (4 loads).
    P_STAGE_A(Asb[0], 0); P_STAGE_BLO(Bsb[0], 0); P_STAGE_BHI(Bsb[0], 0);
    P_STAGE_A(Asb[1], 1); P_STAGE_BLO(Bsb[1], 1);
    WAITVM(4);
    BARRIER();

    bf16x8 af[4][2], bl[2][2], bh[2][2];
#pragma unroll 1
    for (int i = 0; i < 16; ++i) {
        const int tb = 2 * i;
        {   // Pa0
            P_DSA8(Asb[0]); P_DSB(Bsb[0], 0, bl);
            P_STAGE_BHI(Bsb[1], tb + 1);
            P_MMA(0, bl); BARRIER();
        }
        {   // Pb0
            P_DSB(Bsb[0], 32, bh);
            P_STAGE_A(Asb[0], tb + 2); P_STAGE_BLO(Bsb[0], tb + 2);
            WAITVM(4);
            P_MMA(2, bh); BARRIER();
        }
        {   // Pa1
            P_DSA8(Asb[1]); P_DSB(Bsb[1], 0, bl);
            P_STAGE_BHI(Bsb[0], tb + 2);
            P_MMA(0, bl); BARRIER();
        }
        {   // Pb1
            P_DSB(Bsb[1], 32, bh);
            P_STAGE_A(Asb[1], tb + 3); P_STAGE_BLO(Bsb[1], tb + 3);
            WAITVM(4);
            P_MMA(2, bh); BARRIER();
        }
    }
    WAITVM(0);
    __syncthreads();

    // fp32 C store, N = DIM
#pragma unroll
    for (int mt = 0; mt < 4; mt++)
#pragma unroll
        for (int r = 0; r < 4; r++) {
            const int row = m0 + wr * 64 + mt * 16 + quad * 4 + r;
#pragma unroll
            for (int nt = 0; nt < 4; nt++)
                C[(size_t)row * DIM + n0 + wc * 64 + nt * 16 + m16] = acc[mt][nt][r];
        }
}

// ---------------------------------------------------------------------------
// KV-split schedule, LPT-balanced. {bx, t0, t1, slot}.
// ---------------------------------------------------------------------------
__device__ __constant__ short attn_tab[24][4] = {
    {15, 0, 16, 14}, {15, 16, 32, 15}, {7, 0, 16, -1}, {14, 0, 15, 12},
    {13, 0, 14, 10}, {13, 14, 28, 11}, {6, 0, 14, -1}, {10, 0, 11, 4},
    {12, 0, 13, 8},  {12, 13, 26, 9}, {14, 15, 30, 13}, {11, 0, 12, 6},
    {11, 12, 24, 7}, {5, 0, 12, -1}, {10, 11, 22, 5},  {9, 0, 10, 2},
    {2, 0, 6, -1},   {1, 0, 4, -1},  {0, 0, 2, -1},    {3, 0, 8, -1},
    {8, 0, 9, 0},    {8, 9, 18, 1},  {9, 10, 20, 3},   {4, 0, 10, -1},
};

// ---------------------------------------------------------------------------
// Flash attention, no-max softmax, single-buffer staging. Partials: chunk 0
// writes UNNORMALIZED O straight into Y (+ l to Pl); chunk 1 writes Po (+ Pl);
// combine merges in place.
// ---------------------------------------------------------------------------
__global__ __launch_bounds__(256) void attn(const ushort_t* __restrict__ QKV,
                                            const ushort_t* __restrict__ Vt,
                                            ushort_t* __restrict__ Y,
                                            ushort_t* __restrict__ Po,
                                            float* __restrict__ Pl) {
    __shared__ __align__(16) ushort_t Ks[64 * 128];
    __shared__ __align__(16) ushort_t Vs[128 * 64];
    __shared__ __align__(16) ushort_t Ps[4][32 * 72];
    const int lane = threadIdx.x & 63;
    const int wave = threadIdx.x >> 6;
    const int m16 = lane & 15, quad = lane >> 4;
    const int seg = blockIdx.x >> 5;
    const int hb = blockIdx.x & 31;
    const int h = hb & (NH - 1), b = hb >> 4;
    const int kvh = h >> 2;
    const int bx = attn_tab[seg][0];
    const int t0 = attn_tab[seg][1];
    const int t1 = attn_tab[seg][2];
    const int slotl = attn_tab[seg][3];
    const int q0w = bx * 128 + wave * 32;

    const ushort_t* kbase = QKV + (size_t)b * S_LEN * QKV_N + DIM + kvh * HD;
    const ushort_t* vbase = Vt + (size_t)(b * NKV + kvh) * (HD * S_LEN);

    bf16x8 bq[2][4];
#pragma unroll
    for (int g = 0; g < 2; g++)
#pragma unroll
        for (int ks = 0; ks < 4; ks++)
            bq[g][ks] = *(const bf16x8*)&QKV[((size_t)(b * S_LEN + q0w + g * 16 + m16)) * QKV_N +
                                             h * HD + ks * 32 + quad * 8];

    float ls[2] = {0.f, 0.f};
    f32x4 o[2][8];
#pragma unroll
    for (int g = 0; g < 2; g++)
#pragma unroll
        for (int nd = 0; nd < 8; nd++) o[g][nd] = (f32x4){0.f, 0.f, 0.f, 0.f};

    ushort_t* pw = Ps[wave];
    for (int t = t0; t < t1; ++t) {
        const int kv0 = t * 64;
        __syncthreads();
#pragma unroll
        for (int i = 0; i < 4; i++) {
            const int c0 = i * 256 + wave * 64;
            const int ck = c0 + lane;
            const int krow = ck >> 4;
            const int kcol = (ck & 15) ^ (krow & 7);
            GLOAD_LDS16(kbase + (size_t)(kv0 + krow) * QKV_N + kcol * 8, &Ks[c0 * 8]);
            const int vd = ck >> 3;
            const int vcol = (ck & 7) ^ (vd & 7);
            GLOAD_LDS16(vbase + (size_t)vd * S_LEN + kv0 + vcol * 8, &Vs[c0 * 8]);
        }
        __syncthreads();

        f32x4 st[2][4];
#pragma unroll
        for (int g = 0; g < 2; g++)
#pragma unroll
            for (int nt = 0; nt < 4; nt++) st[g][nt] = (f32x4){0.f, 0.f, 0.f, 0.f};
#pragma unroll
        for (int ks = 0; ks < 4; ks++)
#pragma unroll
            for (int nt = 0; nt < 4; nt++) {
                const int row = nt * 16 + m16;
                bf16x8 ak = *(const bf16x8*)&Ks[row * 128 + (((ks * 4 + quad) ^ (row & 7)) * 8)];
#pragma unroll
                for (int g = 0; g < 2; g++)
                    st[g][nt] = __builtin_amdgcn_mfma_f32_16x16x32_bf16(ak, bq[g][ks],
                                                                        st[g][nt], 0, 0, 0);
            }
#pragma unroll
        for (int g = 0; g < 2; g++) {
            const int q0g = q0w + g * 16;
            const int qg = q0g + m16;
            const bool interior = (kv0 + 63 <= q0g);
            float rs = 0.f;
#pragma unroll
            for (int nt = 0; nt < 4; nt++) {
                float p[4];
#pragma unroll
                for (int r = 0; r < 4; r++) {
                    float x = st[g][nt][r] * 0.08838834764831845f;
                    if (!interior) {
                        const int kg = kv0 + nt * 16 + quad * 4 + r;
                        x = (kg > qg) ? NEGBIG : x;
                    }
                    p[r] = __expf(x);
                }
                rs += (p[0] + p[1]) + (p[2] + p[3]);
                uint2 pk = {pk2bf(p[0], p[1]), pk2bf(p[2], p[3])};
                *(uint2*)&pw[(g * 16 + m16) * 72 + nt * 16 + quad * 4] = pk;
            }
            ls[g] += rs;
        }
        __asm__ __volatile__("s_waitcnt lgkmcnt(0)" ::: "memory");
        bf16x8 bp[2][2];
#pragma unroll
        for (int g = 0; g < 2; g++)
#pragma unroll
            for (int kk = 0; kk < 2; kk++)
                bp[g][kk] = *(const bf16x8*)&pw[(g * 16 + m16) * 72 + kk * 32 + quad * 8];
#pragma unroll
        for (int kk = 0; kk < 2; kk++)
#pragma unroll
            for (int nd = 0; nd < 8; nd++) {
                const int vrow = nd * 16 + m16;
                bf16x8 av = *(const bf16x8*)&Vs[vrow * 64 + (((kk * 4 + quad) ^ (vrow & 7)) * 8)];
#pragma unroll
                for (int g = 0; g < 2; g++)
                    o[g][nd] = __builtin_amdgcn_mfma_f32_16x16x32_bf16(av, bp[g][kk],
                                                                       o[g][nd], 0, 0, 0);
            }
    }
    float l_tot[2];
#pragma unroll
    for (int g = 0; g < 2; g++) {
        float v = ls[g];
        v += __shfl_xor(v, 16, 64);
        v += __shfl_xor(v, 32, 64);
        l_tot[g] = v;
    }
    if (slotl < 0) {
        // direct: normalized to Y
#pragma unroll
        for (int g = 0; g < 2; g++) {
            const float inv = 1.0f / l_tot[g];
            const int qg = q0w + g * 16 + m16;
            ushort_t* yp = Y + ((size_t)(b * S_LEN + qg)) * DIM + h * HD;
#pragma unroll
            for (int nd = 0; nd < 8; nd++) {
                uint2 pk = {pk2bf(o[g][nd][0] * inv, o[g][nd][1] * inv),
                            pk2bf(o[g][nd][2] * inv, o[g][nd][3] * inv)};
                *(uint2*)&yp[nd * 16 + quad * 4] = pk;
            }
        }
    } else if ((slotl & 1) == 0) {
        // chunk 0: UNNORMALIZED O straight into Y, l to Pl
        const int slot = ((b * NH + h) << 4) + slotl;
#pragma unroll
        for (int g = 0; g < 2; g++) {
            const int qg = q0w + g * 16 + m16;
            ushort_t* yp = Y + ((size_t)(b * S_LEN + qg)) * DIM + h * HD;
#pragma unroll
            for (int nd = 0; nd < 8; nd++) {
                uint2 pk = {pk2bf(o[g][nd][0], o[g][nd][1]),
                            pk2bf(o[g][nd][2], o[g][nd][3])};
                *(uint2*)&yp[nd * 16 + quad * 4] = pk;
            }
            if (quad == 0) Pl[slot * 128 + wave * 32 + g * 16 + m16] = l_tot[g];
        }
    } else {
        // chunk 1: Po + Pl
        const int slot = ((b * NH + h) << 4) + slotl;
        ushort_t* po = Po + (size_t)(((b * NH + h) << 3) + (slotl >> 1)) * (128 * 128);
#pragma unroll
        for (int g = 0; g < 2; g++) {
            const int ql = wave * 32 + g * 16 + m16;
#pragma unroll
            for (int nd = 0; nd < 8; nd++) {
                uint2 pk = {pk2bf(o[g][nd][0], o[g][nd][1]),
                            pk2bf(o[g][nd][2], o[g][nd][3])};
                *(uint2*)&po[ql * 128 + nd * 16 + quad * 4] = pk;
            }
            if (quad == 0) Pl[slot * 128 + ql] = l_tot[g];
        }
    }
}

// Merge chunk-0 (in Y, unnormalized) with chunk-1 (Po), in place.
__global__ __launch_bounds__(256) void attn_combine(const ushort_t* __restrict__ Po,
                                                    const float* __restrict__ Pl,
                                                    ushort_t* __restrict__ Y) {
    const int R = blockIdx.x * 2 + (threadIdx.x >> 7);
    const int d = threadIdx.x & 127;
    const int q = R & 127;
    const int bx8 = (R >> 7) & 7;
    const int h = (R >> 10) & 15;
    const int b = R >> 14;
    const int hb16 = ((b * NH + h) << 4);
    const float l0 = Pl[(hb16 + bx8 * 2) * 128 + q];
    const float l1 = Pl[(hb16 + bx8 * 2 + 1) * 128 + q];
    const float inv = 1.0f / (l0 + l1);
    const int qg = (bx8 + 8) * 128 + q;
    ushort_t* yp = Y + ((size_t)(b * S_LEN + qg)) * DIM + h * HD + d;
    const float o0 = bf2f(*yp);
    const float o1 = bf2f(Po[(size_t)(((b * NH + h) << 3) + bx8) * (128 * 128) + q * 128 + d]);
    *yp = f2bf((o0 + o1) * inv);
}

extern "C" void kernel_launch(void* const* d_in, const int* in_sizes, int n_in,
                              void* d_out, int out_size, void* d_ws, size_t ws_size,
                              hipStream_t stream) {
    (void)in_sizes; (void)n_in; (void)out_size; (void)ws_size;
    const float* xf  = (const float*)d_in[0];
    const float* Wqf = (const float*)d_in[1];
    const float* Wkf = (const float*)d_in[2];
    const float* Wvf = (const float*)d_in[3];
    const float* Wpf = (const float*)d_in[4];
    const float* gn  = (const float*)d_in[5];
    float* out = (float*)d_out;

    // ws (64 MB):
    //  [ 0,16) xb -> y
    //  [16,40) qkv (V columns unused)
    //  [40,44) vt
    //  [44,56) Wqkvb (dead after gemm_qkv) -> Po [44,52), Pl [52,52.25)
    //  [56,64) Wpb (converted up-front, disjoint from Po/Pl)
    char* ws = (char*)d_ws;
    ushort_t* xb    = (ushort_t*)(ws);
    ushort_t* qkv   = (ushort_t*)(ws + (16ull << 20));
    ushort_t* vt    = (ushort_t*)(ws + (40ull << 20));
    ushort_t* Wqkvb = (ushort_t*)(ws + (44ull << 20));
    ushort_t* Wpb   = (ushort_t*)(ws + (56ull << 20));
    ushort_t* y     = xb;
    ushort_t* Po    = (ushort_t*)(ws + (44ull << 20));   // 8 MB
    float*    Pl    = (float*)(ws + (52ull << 20));      // 256 KB

    const int M = BATCH * S_LEN;  // 4096
    cvt_in<<<dim3(18432), 256, 0, stream>>>(xf, Wqf, Wkf, Wvf, Wpf, xb, Wqkvb, Wpb);
    gemm256_qkv<<<dim3(QKV_N / 256, M / 256), 512, 0, stream>>>(xb, Wqkvb, qkv, vt, gn);
    attn<<<dim3(768, 1, 1), 256, 0, stream>>>(qkv, vt, y, Po, Pl);
    attn_combine<<<dim3(BATCH * NH * 8 * 128 / 2), 256, 0, stream>>>(Po, Pl, y);
    gemm_proj<<<dim3(DIM / 256, M / 128), 512, 0, stream>>>(y, Wpb, out);
}

// Round 8
// 289.790 us; speedup vs baseline: 1.0104x; 1.0104x over previous
//
#include <hip/hip_runtime.h>
#include <hip/hip_bf16.h>

#define DIM 2048
#define NH 16
#define NKV 4
#define HD 128
#define S_LEN 2048
#define BATCH 2
#define QKV_N 3072
#define NEGBIG -1.0e30f

typedef __attribute__((ext_vector_type(8))) short bf16x8;
typedef __attribute__((ext_vector_type(4))) float f32x4;
typedef unsigned short ushort_t;

#define GLOAD_LDS16(gp, lp)                                                       \
    __builtin_amdgcn_global_load_lds(                                             \
        (const __attribute__((address_space(1))) void*)(gp),                      \
        (__attribute__((address_space(3))) void*)(lp), 16, 0, 0)

static __device__ __forceinline__ ushort_t f2bf(float f) {
    union { float f; unsigned u; } v; v.f = f;
    unsigned r = v.u + 0x7fffu + ((v.u >> 16) & 1u);
    return (ushort_t)(r >> 16);
}
static __device__ __forceinline__ float bf2f(ushort_t u) {
    union { unsigned u; float f; } v; v.u = ((unsigned)u) << 16;
    return v.f;
}
static __device__ __forceinline__ unsigned pk2bf(float a, float b) {
    unsigned r;
    __asm__ volatile("v_cvt_pk_bf16_f32 %0, %1, %2" : "=v"(r) : "v"(a), "v"(b));
    return r;
}

// Merged fp32->bf16, 8 floats/thread (16B loads + 16B store per thread).
__global__ __launch_bounds__(256) void cvt_in(const float* __restrict__ x,
                                              const float* __restrict__ Wq,
                                              const float* __restrict__ Wk,
                                              const float* __restrict__ Wv,
                                              const float* __restrict__ Wp,
                                              ushort_t* __restrict__ xb,
                                              ushort_t* __restrict__ Wqkvb,
                                              ushort_t* __restrict__ Wpb) {
    int i = (blockIdx.x * 256 + threadIdx.x) * 8;
    const float* src;
    ushort_t* dst;
    int soff, doff;
    if (i < 8388608) {
        src = x; dst = xb; soff = i; doff = i;
    } else if (i < 14680064) {
        int j = i - 8388608;
        dst = Wqkvb; doff = j;
        if (j < 4194304) { src = Wq; soff = j; }
        else if (j < 5242880) { src = Wk; soff = j - 4194304; }
        else { src = Wv; soff = j - 5242880; }
    } else {
        int j = i - 14680064;
        src = Wp; dst = Wpb; soff = j; doff = j;
    }
    float4 a = *(const float4*)&src[soff];
    float4 b = *(const float4*)&src[soff + 4];
    uint4 o = {pk2bf(a.x, a.y), pk2bf(a.z, a.w), pk2bf(b.x, b.y), pk2bf(b.z, b.w)};
    *(uint4*)&dst[doff] = o;
}

#define FENCE() __asm__ __volatile__("" ::: "memory")
#define BARRIER() do { FENCE(); __builtin_amdgcn_s_barrier(); FENCE(); } while (0)
#define WAITVM(n) __asm__ __volatile__("s_waitcnt vmcnt(" #n ")" ::: "memory")

#define STG(LDSA, GP, rowb) do {                                                  \
    const int r_ = (rowb) + rsub;                                                 \
    GLOAD_LDS16(&(GP)[(size_t)r_ * 2048 + kk0_ + ((csw0 ^ (r_ & 7)) * 8)],        \
                &(LDSA)[(rowb) * 64]);                                            \
} while (0)

// ---------------------------------------------------------------------------
// 256x256 8-phase GEMM (qkv). Single barrier/phase, counted vmcnt(6), XCD
// chunk swizzle. Compiler-placed lgkm waits.
// ---------------------------------------------------------------------------
#define STAGE_HT(AB, BB, kt, ht) do {                                             \
    const int kt_ = (kt) < 31 ? (kt) : 31;                                        \
    const int kk0_ = kt_ * 64;                                                    \
    if ((ht) == 0)      { STG(BB, Bp, w8);       STG(BB, Bp, 64 + w8);  }         \
    else if ((ht) == 1) { STG(BB, Bp, 128 + w8); STG(BB, Bp, 192 + w8); }         \
    else if ((ht) == 2) { STG(AB, Ap, w8);       STG(AB, Ap, 128 + w8); }         \
    else                { STG(AB, Ap, 64 + w8);  STG(AB, Ap, 192 + w8); }         \
} while (0)

#define DSA(mtb, AS) do {                                                         \
    _Pragma("unroll") for (int dm = 0; dm < 2; dm++)                              \
    _Pragma("unroll") for (int ks = 0; ks < 2; ks++) {                            \
        const int row = wr * 128 + ((mtb) + dm) * 16 + m16;                       \
        af[dm][ks] = *(const bf16x8*)&(AS)[row * 64 +                             \
                                           (((ks * 4 + quad) ^ (row & 7)) * 8)];  \
    }                                                                             \
} while (0)

#define DSB(BS) do {                                                              \
    _Pragma("unroll") for (int nt = 0; nt < 4; nt++)                              \
    _Pragma("unroll") for (int ks = 0; ks < 2; ks++) {                            \
        const int row = wc * 64 + nt * 16 + m16;                                  \
        bfr[nt][ks] = *(const bf16x8*)&(BS)[row * 64 +                            \
                                            (((ks * 4 + quad) ^ (row & 7)) * 8)]; \
    }                                                                             \
} while (0)

#define MMA(mtb) do {                                                             \
    __builtin_amdgcn_s_setprio(1);                                                \
    _Pragma("unroll") for (int ks = 0; ks < 2; ks++)                              \
    _Pragma("unroll") for (int dm = 0; dm < 2; dm++)                              \
    _Pragma("unroll") for (int nt = 0; nt < 4; nt++)                              \
        acc[(mtb) + dm][nt] = __builtin_amdgcn_mfma_f32_16x16x32_bf16(            \
            af[dm][ks], bfr[nt][ks], acc[(mtb) + dm][nt], 0, 0, 0);               \
    __builtin_amdgcn_s_setprio(0);                                                \
} while (0)

__global__ __launch_bounds__(512, 2) void gemm256_qkv(const ushort_t* __restrict__ A,
                                                      const ushort_t* __restrict__ B,
                                                      ushort_t* __restrict__ qkv,
                                                      ushort_t* __restrict__ vt,
                                                      const float* __restrict__ gain) {
    __shared__ __align__(16) ushort_t sh[4][256 * 64];  // A0 A1 B0 B1; reused as Cs
    const int t = threadIdx.x;
    const int lane = t & 63;
    const int wave = t >> 6;
    const int m16 = lane & 15;
    const int quad = lane >> 4;
    const int wr = wave >> 2;
    const int wc = wave & 3;
    const int nwg = gridDim.x * gridDim.y;
    const int wgid = blockIdx.y * gridDim.x + blockIdx.x;
    const int wg2 = (wgid & 7) * (nwg >> 3) + (wgid >> 3);
    const int bx = wg2 % gridDim.x;
    const int m0 = (wg2 / gridDim.x) * 256;
    const int n0 = bx * 256;
    const int rsub = lane >> 3;
    const int csw0 = lane & 7;
    const int w8 = wave * 8;
    const ushort_t* Ap = A + (size_t)m0 * 2048;
    const ushort_t* Bp = B + (size_t)n0 * 2048;

    f32x4 acc[8][4];
#pragma unroll
    for (int i = 0; i < 8; i++)
#pragma unroll
        for (int j = 0; j < 4; j++) acc[i][j] = (f32x4){0.f, 0.f, 0.f, 0.f};

    STAGE_HT(sh[0], sh[2], 0, 0);
    STAGE_HT(sh[0], sh[2], 0, 1);
    STAGE_HT(sh[0], sh[2], 0, 2);
    STAGE_HT(sh[0], sh[2], 0, 3);
    STAGE_HT(sh[1], sh[3], 1, 0);
    STAGE_HT(sh[1], sh[3], 1, 1);
    STAGE_HT(sh[1], sh[3], 1, 2);
    WAITVM(6);
    BARRIER();

    bf16x8 bfr[4][2];
#pragma unroll 1
    for (int i = 0; i < 16; ++i) {
        const int tb = 2 * i;
        {   bf16x8 af[2][2];
            DSA(0, sh[0]); DSB(sh[2]);
            STAGE_HT(sh[1], sh[3], tb + 1, 3);
            MMA(0); BARRIER();
        }
        {   bf16x8 af[2][2];
            DSA(2, sh[0]);
            STAGE_HT(sh[0], sh[2], tb + 2, 0);
            MMA(2); BARRIER();
        }
        {   bf16x8 af[2][2];
            DSA(4, sh[0]);
            STAGE_HT(sh[0], sh[2], tb + 2, 1);
            MMA(4); BARRIER();
        }
        {   bf16x8 af[2][2];
            DSA(6, sh[0]);
            STAGE_HT(sh[0], sh[2], tb + 2, 2);
            WAITVM(6);
            MMA(6); BARRIER();
        }
        {   bf16x8 af[2][2];
            DSA(0, sh[1]); DSB(sh[3]);
            STAGE_HT(sh[0], sh[2], tb + 2, 3);
            MMA(0); BARRIER();
        }
        {   bf16x8 af[2][2];
            DSA(2, sh[1]);
            STAGE_HT(sh[1], sh[3], tb + 3, 0);
            MMA(2); BARRIER();
        }
        {   bf16x8 af[2][2];
            DSA(4, sh[1]);
            STAGE_HT(sh[1], sh[3], tb + 3, 1);
            MMA(4); BARRIER();
        }
        {   bf16x8 af[2][2];
            DSA(6, sh[1]);
            STAGE_HT(sh[1], sh[3], tb + 3, 2);
            WAITVM(6);
            MMA(6); BARRIER();
        }
    }
    WAITVM(0);
    __syncthreads();

    // Fused qkv epilogue via 256x256 bf16 C-stage in LDS.
    ushort_t* Cs = &sh[0][0];
#pragma unroll
    for (int mt = 0; mt < 8; mt++)
#pragma unroll
        for (int r = 0; r < 4; r++) {
            const int row = wr * 128 + mt * 16 + quad * 4 + r;
#pragma unroll
            for (int nt = 0; nt < 4; nt++)
                Cs[row * 256 + wc * 64 + nt * 16 + m16] = f2bf(acc[mt][nt][r]);
        }
    __syncthreads();

    if (bx < 10) {
        // Q (bx<8) / K (bx 8,9): tile = 2 heads. RMSNorm + RoPE (+gain).
        const float invf = exp2f(-0.20762050593046f * (float)lane);
        float gg[2];
#pragma unroll
        for (int hh = 0; hh < 2; hh++) gg[hh] = (bx < 8) ? gain[bx * 2 + hh] : 1.0f;
#pragma unroll 2
        for (int i = 0; i < 32; i++) {
            const int row = wave * 32 + i;
            const int m = m0 + row;
            const int s = m & (S_LEN - 1);
            const float fr = (float)s * invf;
            const float c = cosf(fr), sn = sinf(fr);
#pragma unroll
            for (int hh = 0; hh < 2; hh++) {
                float x1 = bf2f(Cs[row * 256 + hh * 128 + lane]);
                float x2 = bf2f(Cs[row * 256 + hh * 128 + 64 + lane]);
                float ss = x1 * x1 + x2 * x2;
#pragma unroll
                for (int mm = 32; mm >= 1; mm >>= 1) ss += __shfl_xor(ss, mm, 64);
                const float rms = rsqrtf(ss * (1.0f / 128.0f) + 1.1920928955078125e-07f);
                x1 *= rms; x2 *= rms;
                ushort_t* dst = qkv + (size_t)m * QKV_N + bx * 256 + hh * 128;
                dst[lane] = f2bf((x1 * c + x2 * sn) * gg[hh]);
                dst[lane + 64] = f2bf((x2 * c - x1 * sn) * gg[hh]);
            }
        }
    } else {
        // V: transpose-out 2 kv heads -> vt[b][kv][d][s]
        const int half = t >> 8;
        const int tt = t & 255;
        const int d = tt >> 1;
        const int so = (tt & 1) * 128;
        const int b = m0 >> 11;
        const int s0 = m0 & (S_LEN - 1);
        const int kv = (bx - 10) * 2 + half;
        ushort_t* dst = vt + ((size_t)(b * NKV + kv) * HD + d) * S_LEN + s0 + so;
#pragma unroll
        for (int j0 = 0; j0 < 128; j0 += 8) {
            ushort_t tmp[8];
#pragma unroll
            for (int j = 0; j < 8; j++) tmp[j] = Cs[(so + j0 + j) * 256 + half * 128 + d];
            *(uint4*)&dst[j0] = *(uint4*)tmp;
        }
    }
}

// ---------------------------------------------------------------------------
// Proj GEMM: BM=128 x BN=256, BK=64, 512 threads. Grid 256 = 1 block/CU.
// 4 phases per 2 K-tiles, single barrier/phase, counted vmcnt(4).
// ---------------------------------------------------------------------------
#define P_STAGE_A(AB, kt) do {                                                    \
    const int kt_ = (kt) < 31 ? (kt) : 31;                                        \
    const int kk0_ = kt_ * 64;                                                    \
    STG(AB, Ap, w8); STG(AB, Ap, 64 + w8);                                        \
} while (0)
#define P_STAGE_BLO(BB, kt) do {                                                  \
    const int kt_ = (kt) < 31 ? (kt) : 31;                                        \
    const int kk0_ = kt_ * 64;                                                    \
    STG(BB, Bp, w8); STG(BB, Bp, 64 + w8);                                        \
} while (0)
#define P_STAGE_BHI(BB, kt) do {                                                  \
    const int kt_ = (kt) < 31 ? (kt) : 31;                                        \
    const int kk0_ = kt_ * 64;                                                    \
    STG(BB, Bp, 128 + w8); STG(BB, Bp, 192 + w8);                                 \
} while (0)

#define P_DSA8(AS) do {                                                           \
    _Pragma("unroll") for (int mt = 0; mt < 4; mt++)                              \
    _Pragma("unroll") for (int ks = 0; ks < 2; ks++) {                            \
        const int row = wr * 64 + mt * 16 + m16;                                  \
        af[mt][ks] = *(const bf16x8*)&(AS)[row * 64 +                             \
                                           (((ks * 4 + quad) ^ (row & 7)) * 8)];  \
    }                                                                             \
} while (0)
#define P_DSB(BS, base, arr) do {                                                 \
    _Pragma("unroll") for (int nt = 0; nt < 2; nt++)                              \
    _Pragma("unroll") for (int ks = 0; ks < 2; ks++) {                            \
        const int row = wc * 64 + (base) + nt * 16 + m16;                         \
        arr[nt][ks] = *(const bf16x8*)&(BS)[row * 64 +                            \
                                            (((ks * 4 + quad) ^ (row & 7)) * 8)]; \
    }                                                                             \
} while (0)

#define P_MMA(ntb, arr) do {                                                      \
    __builtin_amdgcn_s_setprio(1);                                                \
    _Pragma("unroll") for (int ks = 0; ks < 2; ks++)                              \
    _Pragma("unroll") for (int mt = 0; mt < 4; mt++)                              \
    _Pragma("unroll") for (int nt = 0; nt < 2; nt++)                              \
        acc[mt][(ntb) + nt] = __builtin_amdgcn_mfma_f32_16x16x32_bf16(            \
            af[mt][ks], arr[nt][ks], acc[mt][(ntb) + nt], 0, 0, 0);               \
    __builtin_amdgcn_s_setprio(0);                                                \
} while (0)

__global__ __launch_bounds__(512, 2) void gemm_proj(const ushort_t* __restrict__ A,
                                                    const ushort_t* __restrict__ B,
                                                    float* __restrict__ C) {
    __shared__ __align__(16) ushort_t Asb[2][128 * 64];  // 2 x 16 KB
    __shared__ __align__(16) ushort_t Bsb[2][256 * 64];  // 2 x 32 KB
    const int t = threadIdx.x;
    const int lane = t & 63;
    const int wave = t >> 6;
    const int m16 = lane & 15;
    const int quad = lane >> 4;
    const int wr = wave >> 2;
    const int wc = wave & 3;
    const int nwg = gridDim.x * gridDim.y;           // 8 x 32 = 256
    const int wgid = blockIdx.y * gridDim.x + blockIdx.x;
    const int wg2 = (wgid & 7) * (nwg >> 3) + (wgid >> 3);
    const int bx = wg2 % gridDim.x;
    const int m0 = (wg2 / gridDim.x) * 128;
    const int n0 = bx * 256;
    const int rsub = lane >> 3;
    const int csw0 = lane & 7;
    const int w8 = wave * 8;
    const ushort_t* Ap = A + (size_t)m0 * 2048;
    const ushort_t* Bp = B + (size_t)n0 * 2048;

    f32x4 acc[4][4];
#pragma unroll
    for (int i = 0; i < 4; i++)
#pragma unroll
        for (int j = 0; j < 4; j++) acc[i][j] = (f32x4){0.f, 0.f, 0.f, 0.f};

    // Prologue: t0 complete (6 loads), t1.A+Blo (4 loads).
    P_STAGE_A(Asb[0], 0); P_STAGE_BLO(Bsb[0], 0); P_STAGE_BHI(Bsb[0], 0);
    P_STAGE_A(Asb[1], 1); P_STAGE_BLO(Bsb[1], 1);
    WAITVM(4);
    BARRIER();

    bf16x8 af[4][2], bl[2][2], bh[2][2];
#pragma unroll 1
    for (int i = 0; i < 16; ++i) {
        const int tb = 2 * i;
        {   // Pa0
            P_DSA8(Asb[0]); P_DSB(Bsb[0], 0, bl);
            P_STAGE_BHI(Bsb[1], tb + 1);
            P_MMA(0, bl); BARRIER();
        }
        {   // Pb0
            P_DSB(Bsb[0], 32, bh);
            P_STAGE_A(Asb[0], tb + 2); P_STAGE_BLO(Bsb[0], tb + 2);
            WAITVM(4);
            P_MMA(2, bh); BARRIER();
        }
        {   // Pa1
            P_DSA8(Asb[1]); P_DSB(Bsb[1], 0, bl);
            P_STAGE_BHI(Bsb[0], tb + 2);
            P_MMA(0, bl); BARRIER();
        }
        {   // Pb1
            P_DSB(Bsb[1], 32, bh);
            P_STAGE_A(Asb[1], tb + 3); P_STAGE_BLO(Bsb[1], tb + 3);
            WAITVM(4);
            P_MMA(2, bh); BARRIER();
        }
    }
    WAITVM(0);
    __syncthreads();

    // fp32 C store, N = DIM
#pragma unroll
    for (int mt = 0; mt < 4; mt++)
#pragma unroll
        for (int r = 0; r < 4; r++) {
            const int row = m0 + wr * 64 + mt * 16 + quad * 4 + r;
#pragma unroll
            for (int nt = 0; nt < 4; nt++)
                C[(size_t)row * DIM + n0 + wc * 64 + nt * 16 + m16] = acc[mt][nt][r];
        }
}

// ---------------------------------------------------------------------------
// KV-split schedule, LPT-balanced. {bx, t0, t1, slot}.
// ---------------------------------------------------------------------------
__device__ __constant__ short attn_tab[24][4] = {
    {15, 0, 16, 14}, {15, 16, 32, 15}, {7, 0, 16, -1}, {14, 0, 15, 12},
    {13, 0, 14, 10}, {13, 14, 28, 11}, {6, 0, 14, -1}, {10, 0, 11, 4},
    {12, 0, 13, 8},  {12, 13, 26, 9}, {14, 15, 30, 13}, {11, 0, 12, 6},
    {11, 12, 24, 7}, {5, 0, 12, -1}, {10, 11, 22, 5},  {9, 0, 10, 2},
    {2, 0, 6, -1},   {1, 0, 4, -1},  {0, 0, 2, -1},    {3, 0, 8, -1},
    {8, 0, 9, 0},    {8, 9, 18, 1},  {9, 10, 20, 3},   {4, 0, 10, -1},
};

// ---------------------------------------------------------------------------
// Flash attention, no-max softmax, single-buffer global_load_lds staging
// (round-6 passing version, reverted from the racy reg-staged variant).
// ---------------------------------------------------------------------------
__global__ __launch_bounds__(256) void attn(const ushort_t* __restrict__ QKV,
                                            const ushort_t* __restrict__ Vt,
                                            ushort_t* __restrict__ Y,
                                            ushort_t* __restrict__ Po,
                                            float* __restrict__ Pl) {
    __shared__ __align__(16) ushort_t Ks[64 * 128];
    __shared__ __align__(16) ushort_t Vs[128 * 64];
    __shared__ __align__(16) ushort_t Ps[4][32 * 72];
    const int lane = threadIdx.x & 63;
    const int wave = threadIdx.x >> 6;
    const int m16 = lane & 15, quad = lane >> 4;
    const int seg = blockIdx.x >> 5;
    const int hb = blockIdx.x & 31;
    const int h = hb & (NH - 1), b = hb >> 4;
    const int kvh = h >> 2;
    const int bx = attn_tab[seg][0];
    const int t0 = attn_tab[seg][1];
    const int t1 = attn_tab[seg][2];
    const int slotl = attn_tab[seg][3];
    const int q0w = bx * 128 + wave * 32;

    const ushort_t* kbase = QKV + (size_t)b * S_LEN * QKV_N + DIM + kvh * HD;
    const ushort_t* vbase = Vt + (size_t)(b * NKV + kvh) * (HD * S_LEN);

    bf16x8 bq[2][4];
#pragma unroll
    for (int g = 0; g < 2; g++)
#pragma unroll
        for (int ks = 0; ks < 4; ks++)
            bq[g][ks] = *(const bf16x8*)&QKV[((size_t)(b * S_LEN + q0w + g * 16 + m16)) * QKV_N +
                                             h * HD + ks * 32 + quad * 8];

    float ls[2] = {0.f, 0.f};
    f32x4 o[2][8];
#pragma unroll
    for (int g = 0; g < 2; g++)
#pragma unroll
        for (int nd = 0; nd < 8; nd++) o[g][nd] = (f32x4){0.f, 0.f, 0.f, 0.f};

    ushort_t* pw = Ps[wave];
    for (int t = t0; t < t1; ++t) {
        const int kv0 = t * 64;
        __syncthreads();
#pragma unroll
        for (int i = 0; i < 4; i++) {
            const int c0 = i * 256 + wave * 64;
            const int ck = c0 + lane;
            const int krow = ck >> 4;
            const int kcol = (ck & 15) ^ (krow & 7);
            GLOAD_LDS16(kbase + (size_t)(kv0 + krow) * QKV_N + kcol * 8, &Ks[c0 * 8]);
            const int vd = ck >> 3;
            const int vcol = (ck & 7) ^ (vd & 7);
            GLOAD_LDS16(vbase + (size_t)vd * S_LEN + kv0 + vcol * 8, &Vs[c0 * 8]);
        }
        __syncthreads();

        f32x4 st[2][4];
#pragma unroll
        for (int g = 0; g < 2; g++)
#pragma unroll
            for (int nt = 0; nt < 4; nt++) st[g][nt] = (f32x4){0.f, 0.f, 0.f, 0.f};
#pragma unroll
        for (int ks = 0; ks < 4; ks++)
#pragma unroll
            for (int nt = 0; nt < 4; nt++) {
                const int row = nt * 16 + m16;
                bf16x8 ak = *(const bf16x8*)&Ks[row * 128 + (((ks * 4 + quad) ^ (row & 7)) * 8)];
#pragma unroll
                for (int g = 0; g < 2; g++)
                    st[g][nt] = __builtin_amdgcn_mfma_f32_16x16x32_bf16(ak, bq[g][ks],
                                                                        st[g][nt], 0, 0, 0);
            }
#pragma unroll
        for (int g = 0; g < 2; g++) {
            const int q0g = q0w + g * 16;
            const int qg = q0g + m16;
            const bool interior = (kv0 + 63 <= q0g);
            float rs = 0.f;
#pragma unroll
            for (int nt = 0; nt < 4; nt++) {
                float p[4];
#pragma unroll
                for (int r = 0; r < 4; r++) {
                    float x = st[g][nt][r] * 0.08838834764831845f;
                    if (!interior) {
                        const int kg = kv0 + nt * 16 + quad * 4 + r;
                        x = (kg > qg) ? NEGBIG : x;
                    }
                    p[r] = __expf(x);
                }
                rs += (p[0] + p[1]) + (p[2] + p[3]);
                uint2 pk = {pk2bf(p[0], p[1]), pk2bf(p[2], p[3])};
                *(uint2*)&pw[(g * 16 + m16) * 72 + nt * 16 + quad * 4] = pk;
            }
            ls[g] += rs;
        }
        __asm__ __volatile__("s_waitcnt lgkmcnt(0)" ::: "memory");
        bf16x8 bp[2][2];
#pragma unroll
        for (int g = 0; g < 2; g++)
#pragma unroll
            for (int kk = 0; kk < 2; kk++)
                bp[g][kk] = *(const bf16x8*)&pw[(g * 16 + m16) * 72 + kk * 32 + quad * 8];
#pragma unroll
        for (int kk = 0; kk < 2; kk++)
#pragma unroll
            for (int nd = 0; nd < 8; nd++) {
                const int vrow = nd * 16 + m16;
                bf16x8 av = *(const bf16x8*)&Vs[vrow * 64 + (((kk * 4 + quad) ^ (vrow & 7)) * 8)];
#pragma unroll
                for (int g = 0; g < 2; g++)
                    o[g][nd] = __builtin_amdgcn_mfma_f32_16x16x32_bf16(av, bp[g][kk],
                                                                       o[g][nd], 0, 0, 0);
            }
    }
    float l_tot[2];
#pragma unroll
    for (int g = 0; g < 2; g++) {
        float v = ls[g];
        v += __shfl_xor(v, 16, 64);
        v += __shfl_xor(v, 32, 64);
        l_tot[g] = v;
    }
    if (slotl < 0) {
        // direct: normalized to Y
#pragma unroll
        for (int g = 0; g < 2; g++) {
            const float inv = 1.0f / l_tot[g];
            const int qg = q0w + g * 16 + m16;
            ushort_t* yp = Y + ((size_t)(b * S_LEN + qg)) * DIM + h * HD;
#pragma unroll
            for (int nd = 0; nd < 8; nd++) {
                uint2 pk = {pk2bf(o[g][nd][0] * inv, o[g][nd][1] * inv),
                            pk2bf(o[g][nd][2] * inv, o[g][nd][3] * inv)};
                *(uint2*)&yp[nd * 16 + quad * 4] = pk;
            }
        }
    } else if ((slotl & 1) == 0) {
        // chunk 0: UNNORMALIZED O straight into Y, l to Pl
        const int slot = ((b * NH + h) << 4) + slotl;
#pragma unroll
        for (int g = 0; g < 2; g++) {
            const int qg = q0w + g * 16 + m16;
            ushort_t* yp = Y + ((size_t)(b * S_LEN + qg)) * DIM + h * HD;
#pragma unroll
            for (int nd = 0; nd < 8; nd++) {
                uint2 pk = {pk2bf(o[g][nd][0], o[g][nd][1]),
                            pk2bf(o[g][nd][2], o[g][nd][3])};
                *(uint2*)&yp[nd * 16 + quad * 4] = pk;
            }
            if (quad == 0) Pl[slot * 128 + wave * 32 + g * 16 + m16] = l_tot[g];
        }
    } else {
        // chunk 1: Po + Pl
        const int slot = ((b * NH + h) << 4) + slotl;
        ushort_t* po = Po + (size_t)(((b * NH + h) << 3) + (slotl >> 1)) * (128 * 128);
#pragma unroll
        for (int g = 0; g < 2; g++) {
            const int ql = wave * 32 + g * 16 + m16;
#pragma unroll
            for (int nd = 0; nd < 8; nd++) {
                uint2 pk = {pk2bf(o[g][nd][0], o[g][nd][1]),
                            pk2bf(o[g][nd][2], o[g][nd][3])};
                *(uint2*)&po[ql * 128 + nd * 16 + quad * 4] = pk;
            }
            if (quad == 0) Pl[slot * 128 + ql] = l_tot[g];
        }
    }
}

// Merge chunk-0 (in Y, unnormalized) with chunk-1 (Po), in place.
// 8 ushorts/thread (uint4 traffic); 16 rows per 256-thread block.
__global__ __launch_bounds__(256) void attn_combine(const ushort_t* __restrict__ Po,
                                                    const float* __restrict__ Pl,
                                                    ushort_t* __restrict__ Y) {
    const int rid = blockIdx.x * 16 + (threadIdx.x >> 4);
    const int d0 = (threadIdx.x & 15) * 8;
    const int q = rid & 127;
    const int bx8 = (rid >> 7) & 7;
    const int h = (rid >> 10) & 15;
    const int b = rid >> 14;
    const int hb16 = ((b * NH + h) << 4);
    const float l0 = Pl[(hb16 + bx8 * 2) * 128 + q];
    const float l1 = Pl[(hb16 + bx8 * 2 + 1) * 128 + q];
    const float inv = 1.0f / (l0 + l1);
    const int qg = (bx8 + 8) * 128 + q;
    ushort_t* yp = Y + ((size_t)(b * S_LEN + qg)) * DIM + h * HD + d0;
    const ushort_t* pp = Po + (size_t)(((b * NH + h) << 3) + bx8) * (128 * 128) + q * 128 + d0;
    ushort_t yv[8], pv[8], ov[8];
    *(uint4*)yv = *(const uint4*)yp;
    *(uint4*)pv = *(const uint4*)pp;
#pragma unroll
    for (int j = 0; j < 8; j++) ov[j] = f2bf((bf2f(yv[j]) + bf2f(pv[j])) * inv);
    *(uint4*)yp = *(uint4*)ov;
}

extern "C" void kernel_launch(void* const* d_in, const int* in_sizes, int n_in,
                              void* d_out, int out_size, void* d_ws, size_t ws_size,
                              hipStream_t stream) {
    (void)in_sizes; (void)n_in; (void)out_size; (void)ws_size;
    const float* xf  = (const float*)d_in[0];
    const float* Wqf = (const float*)d_in[1];
    const float* Wkf = (const float*)d_in[2];
    const float* Wvf = (const float*)d_in[3];
    const float* Wpf = (const float*)d_in[4];
    const float* gn  = (const float*)d_in[5];
    float* out = (float*)d_out;

    // ws (64 MB):
    //  [ 0,16) xb -> y
    //  [16,40) qkv (V columns unused)
    //  [40,44) vt
    //  [44,56) Wqkvb (dead after gemm_qkv) -> Po [44,52), Pl [52,52.25)
    //  [56,64) Wpb (converted up-front, disjoint from Po/Pl)
    char* ws = (char*)d_ws;
    ushort_t* xb    = (ushort_t*)(ws);
    ushort_t* qkv   = (ushort_t*)(ws + (16ull << 20));
    ushort_t* vt    = (ushort_t*)(ws + (40ull << 20));
    ushort_t* Wqkvb = (ushort_t*)(ws + (44ull << 20));
    ushort_t* Wpb   = (ushort_t*)(ws + (56ull << 20));
    ushort_t* y     = xb;
    ushort_t* Po    = (ushort_t*)(ws + (44ull << 20));   // 8 MB
    float*    Pl    = (float*)(ws + (52ull << 20));      // 256 KB

    const int M = BATCH * S_LEN;  // 4096
    cvt_in<<<dim3(9216), 256, 0, stream>>>(xf, Wqf, Wkf, Wvf, Wpf, xb, Wqkvb, Wpb);
    gemm256_qkv<<<dim3(QKV_N / 256, M / 256), 512, 0, stream>>>(xb, Wqkvb, qkv, vt, gn);
    attn<<<dim3(768, 1, 1), 256, 0, stream>>>(qkv, vt, y, Po, Pl);
    attn_combine<<<dim3(2048), 256, 0, stream>>>(Po, Pl, y);
    gemm_proj<<<dim3(DIM / 256, M / 128), 512, 0, stream>>>(y, Wpb, out);
}